// Round 7
// baseline (84.653 us; speedup 1.0000x reference)
//
#include <hip/hip_runtime.h>

#define N_ 64
#define C_ 64
#define T_ 256
#define V_ 25
#define R_ 8
#define O_ 64
constexpr int TV = T_ * V_;           // 6400
constexpr float INV_T = 1.0f / (float)T_;
constexpr int TC = 16;                // t's per fused block
constexpr int UP = 40;                // padded u extent in LDS (80B rows)
constexpr int DP = 32;                // padded u,v extent of dT in global

typedef __attribute__((ext_vector_type(8))) short s8v;   // 8 bf16 = 4 VGPR
typedef __attribute__((ext_vector_type(4))) float f4v;   // MFMA acc

__device__ __forceinline__ unsigned short f2bf(float f) {   // RNE f32->bf16
    union { float f; unsigned u; } v; v.f = f;
    unsigned r = v.u + 0x7FFFu + ((v.u >> 16) & 1u);
    return (unsigned short)(r >> 16);
}

// -------- k_mean: xm[n][c][v] = mean_t x[n][c][t][v]  (proven ~19us)
__global__ __launch_bounds__(256) void k_mean(const float* __restrict__ x,
                                              float* __restrict__ xm) {
    __shared__ float part[8 * V_];
    const int bid = blockIdx.x;           // n*C + c
    const int tid = threadIdx.x;
    const float* xp = x + (size_t)bid * TV;
    if (tid < 200) {
        const int vid = tid % V_;
        const int seg = tid / V_;
        float s = 0.f;
        const float* p = xp + seg * 32 * V_ + vid;
        #pragma unroll
        for (int j = 0; j < 32; ++j) s += p[j * V_];
        part[tid] = s;
    }
    __syncthreads();
    if (tid < V_) {
        float s = 0.f;
        #pragma unroll
        for (int k = 0; k < 8; ++k) s += part[k * V_ + tid];
        xm[(size_t)bid * V_ + tid] = s * INV_T;
    }
}

// -------- k_dmat: dT[n][o][v][u] = d(u,v) bf16, zero-padded to 32x32.
// d(u,v) = sum_r w4[o,r]*tanh(x1[n,r,u]-x2[n,r,v]) + b4[o] + A[u,v]
// Transposed+padded so k_F's B-frags are single aligned b128 loads, maskless.
__global__ __launch_bounds__(256) void k_dmat(const float* __restrict__ xm,
                                              const float* __restrict__ A,
                                              const float* __restrict__ w1,
                                              const float* __restrict__ b1,
                                              const float* __restrict__ w2,
                                              const float* __restrict__ b2,
                                              const float* __restrict__ w4,
                                              const float* __restrict__ b4,
                                              unsigned short* __restrict__ dT) {
    __shared__ float xms[C_][V_];
    __shared__ float x1s[R_][V_];
    __shared__ float x2s[R_][V_];
    const int n  = blockIdx.x;
    const int og = blockIdx.y * 16;
    const int tid = threadIdx.x;

    for (int i = tid; i < C_ * V_; i += 256)
        xms[i / V_][i % V_] = xm[(size_t)n * C_ * V_ + i];
    __syncthreads();

    for (int i = tid; i < 2 * R_ * V_; i += 256) {
        const int j = i % (R_ * V_);
        const int r = j / V_, v = j % V_;
        const bool first = (i < R_ * V_);
        const float* w = first ? w1 : w2;
        float acc = first ? b1[r] : b2[r];
        #pragma unroll
        for (int c = 0; c < C_; ++c) acc += w[r * C_ + c] * xms[c][v];
        if (first) x1s[r][v] = acc;
        else       x2s[r][v] = acc;
    }
    __syncthreads();

    unsigned short* dn = dT + (size_t)n * O_ * DP * DP;
    for (int p = tid; p < DP * DP; p += 256) {       // p = v*32+u, coalesced in u
        const int v = p >> 5, u = p & 31;
        if (u < V_ && v < V_) {
            float adjr[R_];
            #pragma unroll
            for (int r = 0; r < R_; ++r) adjr[r] = tanhf(x1s[r][u] - x2s[r][v]);
            const float a = A[u * V_ + v];
            #pragma unroll
            for (int oo = 0; oo < 16; ++oo) {
                const int o = og + oo;
                float acc = b4[o];
                #pragma unroll
                for (int r = 0; r < R_; ++r) acc = fmaf(w4[o * R_ + r], adjr[r], acc);
                dn[(size_t)o * DP * DP + p] = f2bf(acc + a);   // ALPHA == 1
            }
        } else {
            #pragma unroll
            for (int oo = 0; oo < 16; ++oo)
                dn[(size_t)(og + oo) * DP * DP + p] = 0;
        }
    }
}

// -------- k_F: fused GEMM1 (x3 = w3*x + b3, MFMA, global->reg B-frags) ->
//          LDS x3b -> GEMM2 (out = x3 @ dT, MFMA, dT b128 direct from global).
// 512 thr (8 waves), 80KB LDS -> 2 blocks/CU; ONE barrier.
__global__ __launch_bounds__(512, 4) void k_F(const float* __restrict__ x,
                                              const float* __restrict__ w3,
                                              const float* __restrict__ b3,
                                              const unsigned short* __restrict__ dT,
                                              float* __restrict__ out) {
    __shared__ __align__(16) unsigned short x3b[O_][TC][UP];   // 80 KB bf16

    const int n    = blockIdx.y;
    const int tc   = blockIdx.x;
    const int tid  = threadIdx.x;
    const int lane = tid & 63;
    const int wave = tid >> 6;      // 0..7
    const int l16  = lane & 15;
    const int lg   = lane >> 4;     // 0..3

    // zero the u-pad [25,32) that GEMM2's K=32 reads (disjoint from GEMM1 writes)
    #pragma unroll
    for (int p = 0; p < 2; ++p) {
        const int pair = tid + 512 * p;        // 0..1023 = (o,t)
        const int o = pair >> 4, t = pair & 15;
        #pragma unroll
        for (int u = 25; u < 32; ++u) x3b[o][t][u] = 0;
    }

    // hoist all w3 A-frags: afr[m][kh] elem j = w3[m*16+l16][kh*32+lg*8+j]
    s8v afr[4][2];
    #pragma unroll
    for (int m = 0; m < 4; ++m) {
        #pragma unroll
        for (int kh = 0; kh < 2; ++kh) {
            const float* wp = w3 + (m * 16 + l16) * C_ + kh * 32 + lg * 8;
            s8v f;
            #pragma unroll
            for (int j = 0; j < 8; ++j) f[j] = (short)f2bf(wp[j]);
            afr[m][kh] = f;
        }
    }
    f4v b3r[4];
    #pragma unroll
    for (int m = 0; m < 4; ++m)
        b3r[m] = *(const f4v*)(b3 + m * 16 + lg * 4);

    // ---- GEMM1: 25 pos-tiles of 16, wave-strided (proven pattern)
    const float* xbase = x + (size_t)n * C_ * TV + tc * (TC * V_);
    #pragma unroll 1
    for (int i = 0; i < 4; ++i) {
        const int nt = wave + 8 * i;           // wave-uniform branch
        if (nt < 25) {
            const int pos = nt * 16 + l16;     // < 400
            const int t = pos / 25, u = pos - 25 * t;
            s8v bfr[2];
            #pragma unroll
            for (int kh = 0; kh < 2; ++kh) {
                s8v f;
                #pragma unroll
                for (int j = 0; j < 8; ++j)
                    f[j] = (short)f2bf(xbase[(size_t)(kh * 32 + lg * 8 + j) * TV + pos]);
                bfr[kh] = f;
            }
            #pragma unroll
            for (int m = 0; m < 4; ++m) {
                f4v acc = (f4v)0.f;
                acc = __builtin_amdgcn_mfma_f32_16x16x32_bf16(afr[m][0], bfr[0], acc, 0, 0, 0);
                acc = __builtin_amdgcn_mfma_f32_16x16x32_bf16(afr[m][1], bfr[1], acc, 0, 0, 0);
                // C: col=l16=pos, row=lg*4+r=o-in-tile (verified layout)
                #pragma unroll
                for (int r = 0; r < 4; ++r)
                    x3b[m * 16 + lg * 4 + r][t][u] = f2bf(acc[r] + b3r[m][r]);
            }
        }
    }
    __syncthreads();

    // ---- GEMM2: wave w owns o = w*8..w*8+7. A = x3b[o] (K=32 zero-padded),
    //      B = dT[o] via single b128 loads (coalesced 1024B/wave, L2-resident).
    const unsigned short* dn = dT + (size_t)n * O_ * DP * DP;
    float* on = out + (size_t)n * O_ * TV + tc * (TC * V_);
    #pragma unroll
    for (int oo = 0; oo < 8; ++oo) {
        const int o = wave * 8 + oo;
        const unsigned short* dp = dn + (size_t)o * DP * DP;
        const s8v bv0 = *(const s8v*)(dp + l16 * DP + lg * 8);        // B: col=v=l16
        const s8v bv1 = *(const s8v*)(dp + (16 + l16) * DP + lg * 8); // v=16+l16 (>=25 rows are 0)
        const s8v av  = *(const s8v*)&x3b[o][l16][lg * 8];            // A: row=t=l16, k=u
        f4v c0 = (f4v)0.f, c1 = (f4v)0.f;
        c0 = __builtin_amdgcn_mfma_f32_16x16x32_bf16(av, bv0, c0, 0, 0, 0);
        c1 = __builtin_amdgcn_mfma_f32_16x16x32_bf16(av, bv1, c1, 0, 0, 0);
        float* ob = on + (size_t)o * TV;
        #pragma unroll
        for (int r = 0; r < 4; ++r) {
            const int t = lg * 4 + r;                                 // C: row=t, col=v
            ob[t * 25 + l16] = c0[r];
            if (l16 < 9) ob[t * 25 + 16 + l16] = c1[r];
        }
    }
}

extern "C" void kernel_launch(void* const* d_in, const int* in_sizes, int n_in,
                              void* d_out, int out_size, void* d_ws, size_t ws_size,
                              hipStream_t stream) {
    const float* x  = (const float*)d_in[0];
    const float* A  = (const float*)d_in[1];
    const float* w1 = (const float*)d_in[2];
    const float* b1 = (const float*)d_in[3];
    const float* w2 = (const float*)d_in[4];
    const float* b2 = (const float*)d_in[5];
    const float* w3 = (const float*)d_in[6];
    const float* b3 = (const float*)d_in[7];
    const float* w4 = (const float*)d_in[8];
    const float* b4 = (const float*)d_in[9];

    float* out = (float*)d_out;
    float* xm  = (float*)d_ws;                                          // 0.41 MB f32
    unsigned short* dTm = (unsigned short*)(xm + (size_t)N_ * C_ * V_); // N*O*32*32 bf16 (8.4 MB)

    k_mean<<<N_ * C_, 256, 0, stream>>>(x, xm);
    k_dmat<<<dim3(N_, 4), 256, 0, stream>>>(xm, A, w1, b1, w2, b2, w4, b4, dTm);
    k_F<<<dim3(T_ / TC, N_), 512, 0, stream>>>(x, w3, b3, dTm, out);
}